// Round 7
// baseline (181.947 us; speedup 1.0000x reference)
//
#include <hip/hip_runtime.h>

#define T_SEQ 2048
#define N_B   4
#define N_H   16
#define D_H   64
#define EMB   1024
#define CSC   0.18033688011f  // log2(e) / sqrt(64), folded into Q at projection

typedef __attribute__((ext_vector_type(8))) short   vshort8;   // 8 bf16 (4 VGPRs)
typedef __attribute__((ext_vector_type(4))) float   vfloat4;   // 16x16 C/D
typedef __attribute__((ext_vector_type(16))) float  vfloat16;  // 32x32 C/D

__device__ __forceinline__ ushort f2bf(float f) {
  union { float f; unsigned u; } v; v.f = f;
  unsigned u = v.u;
  return (ushort)((u + 0x7fffu + ((u >> 16) & 1u)) >> 16);  // RNE
}
__device__ __forceinline__ unsigned pk2bf(float a, float b) {  // [bf(a),bf(b)] in mem
  return (unsigned)f2bf(a) | ((unsigned)f2bf(b) << 16);
}
__device__ __forceinline__ float bf2f(ushort b) {
  union { unsigned u; float f; } v; v.u = ((unsigned)b) << 16;
  return v.f;
}
__device__ __forceinline__ float fexp2(float x) {
#if __has_builtin(__builtin_amdgcn_exp2f)
  return __builtin_amdgcn_exp2f(x);
#else
  return exp2f(x);
#endif
}
// pack hi16(lo),hi16(hi) -> [bf_trunc(lo), bf_trunc(hi)] in memory (1 v_perm)
__device__ __forceinline__ unsigned permhi(float hi, float lo) {
  union { float f; unsigned u; } a, b; a.f = hi; b.f = lo;
#if __has_builtin(__builtin_amdgcn_perm)
  return __builtin_amdgcn_perm(a.u, b.u, 0x07060302u);
#else
  return (a.u & 0xFFFF0000u) | (b.u >> 16);
#endif
}
// v_permlane32_swap_b32: cross-half exchange for the P C->A transpose.
//   a' = { a (lanes<32) | b[lane-32] (lanes>=32) }
//   b' = { a[lane+32] (lanes<32) | b (lanes>=32) }
__device__ __forceinline__ void plswap(unsigned &a, unsigned &b) {
  asm("v_permlane32_swap_b32 %0, %1" : "+v"(a), "+v"(b));
}
__device__ __forceinline__ vshort8 cvt8(const float* p) {
  float4 w0 = *(const float4*)(p);
  float4 w1 = *(const float4*)(p + 4);
  vshort8 t;
  t[0] = (short)f2bf(w0.x); t[1] = (short)f2bf(w0.y);
  t[2] = (short)f2bf(w0.z); t[3] = (short)f2bf(w0.w);
  t[4] = (short)f2bf(w1.x); t[5] = (short)f2bf(w1.y);
  t[6] = (short)f2bf(w1.z); t[7] = (short)f2bf(w1.w);
  return t;
}
// async global->LDS DMA, 16 B per lane, lands at lds_base + lane*16.
// lds base must be wave-uniform; global source is per-lane (pre-swizzled).
__device__ __forceinline__ void gload_lds16(const uint4* gp, uint4* lp) {
  __builtin_amdgcn_global_load_lds(
      (const __attribute__((address_space(1))) void*)gp,
      (__attribute__((address_space(3))) void*)lp, 16, 0, 0);
}

// ---- 32-lane-fragment blob layouts (uint4 = 8 bf16 = one lane-frag) ----
// Q/K: uint4 idx = ((bh*64 + t32)*4 + dstep)*64 + l31*2 + h
//      lane (l31,h) frag = X[t = 32*t32 + l31][d = 16*dstep + 8*h + 0..7]
// V  : uint4 idx = (((bh*32 + s64)*4 + step)*2 + dblk)*64 + l31*2 + h
//      lane (l31,h) frag = V[s = 64*s64 + 16*step + 8*h + 0..7][d = 32*dblk + l31]
// Per (bh, 64-s tile): K region = Kb + bh*16384 + ss*512 (512 uint4, 8 KB)

// ---------------- W pre-conversion (runs once, 1 wave) ----------------
__global__ void wconv(const float* __restrict__ Wq, const float* __restrict__ Wk,
                      const float* __restrict__ Wv, ushort* __restrict__ Wb) {
  const int lane = threadIdx.x & 63;
  const int l15  = lane & 15;
  const int quad = lane >> 4;
  const float* Ws[3] = {Wq, Wk, Wv};
#pragma unroll
  for (int m = 0; m < 3; ++m)
#pragma unroll
    for (int kc = 0; kc < 2; ++kc)
#pragma unroll
      for (int nt = 0; nt < 4; ++nt) {
        vshort8 t = cvt8(Ws[m] + (nt * 16 + l15) * D_H + kc * 32 + quad * 8);
        *(vshort8*)(&Wb[(((m * 2 + kc) * 4 + nt) * 64 + lane) * 8]) = t;
      }
}

// ---------------- QKV projection (16x16 MFMA compute, 32-frag stores) -------
__global__ __launch_bounds__(256, 4) void proj_qkv(
    const float* __restrict__ x, const ushort* __restrict__ Wb,
    uint2* __restrict__ Qb, uint2* __restrict__ Kb, uint2* __restrict__ Vb) {
  const int wid  = threadIdx.x >> 6;
  const int lane = threadIdx.x & 63;
  const int l15  = lane & 15;
  const int q    = lane >> 4;
  const int gw    = blockIdx.x * 4 + wid;   // [0,8192)
  const int strip = gw >> 4;                // 16-row strip over B*T
  const int hd    = gw & 15;
  const int r0    = strip * 16;
  const int b     = r0 >> 11;
  const int bh    = b * N_H + hd;
  const int ts    = (r0 & (T_SEQ - 1)) >> 4;  // strip index within head [0,128)

  // x frag: lane holds x[r0+l15][hd*64 + kc*32 + q*8 + j]
  vshort8 afr[2];
  {
    const float* xp = x + (size_t)(r0 + l15) * EMB + hd * D_H + q * 8;
    afr[0] = cvt8(xp);
    afr[1] = cvt8(xp + 32);
  }

  uint2* Bs[3] = {Qb, Kb, Vb};
#pragma unroll
  for (int m = 0; m < 3; ++m) {
    vshort8 wf[2][4];
#pragma unroll
    for (int kc = 0; kc < 2; ++kc)
#pragma unroll
      for (int nt = 0; nt < 4; ++nt)
        wf[kc][nt] = *(const vshort8*)(&Wb[(((m * 2 + kc) * 4 + nt) * 64 + lane) * 8]);
    vfloat4 acc[4];
#pragma unroll
    for (int nt = 0; nt < 4; ++nt) acc[nt] = (vfloat4){0.f, 0.f, 0.f, 0.f};
#pragma unroll
    for (int kc = 0; kc < 2; ++kc)
#pragma unroll
      for (int nt = 0; nt < 4; ++nt)
        acc[nt] = (m < 2)
          ? __builtin_amdgcn_mfma_f32_16x16x32_bf16(wf[kc][nt], afr[kc], acc[nt], 0, 0, 0)
          : __builtin_amdgcn_mfma_f32_16x16x32_bf16(afr[kc], wf[kc][nt], acc[nt], 0, 0, 0);
    uint2* B = Bs[m];
#pragma unroll
    for (int nt = 0; nt < 4; ++nt) {
      vfloat4 a = acc[nt];
      if (m == 0) { a[0] *= CSC; a[1] *= CSC; a[2] *= CSC; a[3] *= CSC; }
      uint2 w;
      w.x = pk2bf(a[0], a[1]);
      w.y = pk2bf(a[2], a[3]);
      size_t idx;
      if (m < 2) {
        // swapped C: lane holds (d = 16nt+4q+r, t = l15); t32 = ts>>1
        idx = ((size_t)(bh * 64 + (ts >> 1)) * 4 + nt) * 128
              + (l15 + 16 * (ts & 1)) * 4 + q;
      } else {
        // normal C: lane holds (s = 16(ts&3)+4q+r local in s64, d = 16nt+l15)
        idx = (((size_t)(bh * 32 + (ts >> 2)) * 4 + (ts & 3)) * 2 + (nt >> 1)) * 128
              + 64 * (nt & 1) + l15 * 4 + q;
      }
      B[idx] = w;
    }
  }
}

// ---------------- fused flash attention (no-max softmax) + V residual -------
// Wave = 64 q-rows (2 t32-blocks), block = 4 waves (256 t) of one (b,h).
// K ONLY staged to LDS (its load is consumed at iteration top = exposed
// latency in r0; V's global-load latency is covered in-iteration by
// QK+softmax, proven r0).  Double-buffered async global_load_lds, one
// __syncthreads per tile; DMA latency hides under ~2300 cyc of compute.
// Staging source is PRE-SWIZZLED (lane ln fetches frag (ln&31)*2+(ln>>5))
// so LDS is written linearly and the K read is `+lane` = 1024 contiguous
// bytes per wave = 2 lanes/bank = conflict-free (r6 had 4.19M conflicts
// from the `+lo` stride-32B read).  LDS budget: 8 reads + 8 DMA-writes per
// tile per CU-pair ~ 320 clk < 516 clk MFMA (r6 staged K+V: LDS-bound).
// Per-wave register state = r0's proven 124 VGPR + 1 pointer (r4/r5/r6
// lesson: the unified file at 2 waves/SIMD spills past ~128 arch regs).
__global__ __launch_bounds__(256, 2) void attn_fused(
    const uint4* __restrict__ Qb, const uint4* __restrict__ Kb,
    const uint4* __restrict__ Vb, float* __restrict__ out) {
  const int tid  = threadIdx.x;
  const int wid  = tid >> 6;
  const int lane = tid & 63;
  const int l31  = lane & 31;
  const int h    = lane >> 5;

  // XCD swizzle: 16 consecutive per-XCD slots share a bh -> K/V stay in that L2
  const int blk  = blockIdx.x;                 // [0,512)
  const int work = (blk & 7) * 64 + (blk >> 3);
  const int bh   = work >> 3;
  const int tblk8 = work & 7;
  const int b = bh >> 4, hh = bh & 15;
  const int T64 = tblk8 * 4 + wid;             // this wave's 64-t chunk [0,32)

  const int lo = l31 * 2 + h;                  // lane offset in uint4 units

  // K tile dbuf: [2][8 chunks x 64 uint4] = 2 x 8 KB
  __shared__ uint4 sK[2][512];

  // wave w stages chunks 2w, 2w+1; source pre-swizzled by +lo so that
  // LDS slot ln holds the frag lane ln reads (linear dest, linear read).
  const uint4* gp = Kb + (size_t)bh * 16384 + wid * 128 + lo;
  uint4* ldsA = &sK[0][wid * 128];
  uint4* ldsB = &sK[1][wid * 128];

  gload_lds16(gp, ldsA);                       // prologue: K tile 0 -> buf0
  gload_lds16(gp + 64, ldsA + 64);
  gp += 512;

  // Q B-frags: lane holds Q[t = 32*t32 + l31][d = 16ds + 8h + j] * CSC
  vshort8 qf[2][4];
#pragma unroll
  for (int tb = 0; tb < 2; ++tb)
#pragma unroll
    for (int ds = 0; ds < 4; ++ds)
      qf[tb][ds] = *(const vshort8*)&Qb[((size_t)(bh * 64 + 2 * T64 + tb) * 4 + ds) * 64 + lo];

  vfloat16 oacc[2][2];
#pragma unroll
  for (int tb = 0; tb < 2; ++tb)
#pragma unroll
    for (int db = 0; db < 2; ++db)
#pragma unroll
      for (int i = 0; i < 16; ++i) oacc[tb][db][i] = 0.f;
  float lsum[2] = {0.f, 0.f};

  __syncthreads();                             // K tile 0 landed

#pragma unroll 1
  for (int ss = 0; ss < 32; ++ss) {            // 32 s-tiles of 64
    if (ss < 31) {                             // stage K tile ss+1 -> other buf
      uint4* ld = (ss & 1) ? ldsA : ldsB;
      gload_lds16(gp, ld);
      gload_lds16(gp + 64, ld + 64);
      gp += 512;
    }

    // V B-frags from global (latency covered by QK+softmax below, as in r0):
    // lane holds V[s = 64ss + 16st + 8h + j][d = 32db + l31]
    vshort8 vf[4][2];
#pragma unroll
    for (int st = 0; st < 4; ++st)
#pragma unroll
      for (int db = 0; db < 2; ++db)
        vf[st][db] = *(const vshort8*)&Vb[(((size_t)(bh * 32 + ss) * 4 + st) * 2 + db) * 64 + lo];

    // K A-frags from LDS (conflict-free, short latency):
    // slot ln of chunk (sb*4+ds) holds K[s = 64ss + 32sb + l31][d = 16ds+8h+j]
    const uint4* lb = sK[ss & 1];
    vshort8 kf[2][4];
#pragma unroll
    for (int sb = 0; sb < 2; ++sb)
#pragma unroll
      for (int ds = 0; ds < 4; ++ds)
        kf[sb][ds] = *(const vshort8*)&lb[(sb * 4 + ds) * 64 + lane];

#pragma unroll
    for (int tb = 0; tb < 2; ++tb) {
      // S^T = K*Q^T : C holds (s-local = (r&3)+8(r>>2)+4h + 32sb, t = l31)
      vfloat16 sacc[2];
#pragma unroll
      for (int sb = 0; sb < 2; ++sb)
#pragma unroll
        for (int i = 0; i < 16; ++i) sacc[sb][i] = 0.f;
      __builtin_amdgcn_s_setprio(1);
#pragma unroll
      for (int sb = 0; sb < 2; ++sb)
#pragma unroll
        for (int ds = 0; ds < 4; ++ds)
          sacc[sb] = __builtin_amdgcn_mfma_f32_32x32x16_bf16(kf[sb][ds], qf[tb][ds], sacc[sb], 0, 0, 0);
      __builtin_amdgcn_s_setprio(0);

      // no-max softmax, 4-way partial sums (breaks the serial add chain)
      float p[2][16];
      float s0 = 0.f, s1 = 0.f, s2 = 0.f, s3 = 0.f;
#pragma unroll
      for (int sb = 0; sb < 2; ++sb)
#pragma unroll
        for (int r = 0; r < 16; r += 4) {
          p[sb][r + 0] = fexp2(sacc[sb][r + 0]); s0 += p[sb][r + 0];
          p[sb][r + 1] = fexp2(sacc[sb][r + 1]); s1 += p[sb][r + 1];
          p[sb][r + 2] = fexp2(sacc[sb][r + 2]); s2 += p[sb][r + 2];
          p[sb][r + 3] = fexp2(sacc[sb][r + 3]); s3 += p[sb][r + 3];
        }
      lsum[tb] += (s0 + s1) + (s2 + s3);

      // in-register C->A transpose of P via permlane32_swap:
      // own packs: OL = s 16g+4h+{0..3}, OH = s 16g+8+4h+{0..3} (local in sb)
#pragma unroll
      for (int sb = 0; sb < 2; ++sb)
#pragma unroll
        for (int g = 0; g < 2; ++g) {
          unsigned OL0 = permhi(p[sb][8 * g + 1], p[sb][8 * g + 0]);
          unsigned OL1 = permhi(p[sb][8 * g + 3], p[sb][8 * g + 2]);
          unsigned OH0 = permhi(p[sb][8 * g + 5], p[sb][8 * g + 4]);
          unsigned OH1 = permhi(p[sb][8 * g + 7], p[sb][8 * g + 6]);
          plswap(OL0, OH0);   // OL0' = {own OL0 | partner OH0}, OH0' = {partner OL0 | own OH0}
          plswap(OL1, OH1);
          union { unsigned u[4]; vshort8 v; } pa;
          pa.u[0] = OL0; pa.u[1] = OL1; pa.u[2] = OH0; pa.u[3] = OH1;
          const int st = 2 * sb + g;
          __builtin_amdgcn_s_setprio(1);
#pragma unroll
          for (int db = 0; db < 2; ++db)
            oacc[tb][db] = __builtin_amdgcn_mfma_f32_32x32x16_bf16(pa.v, vf[st][db], oacc[tb][db], 0, 0, 0);
          __builtin_amdgcn_s_setprio(0);
        }
    }

    __syncthreads();   // next K tile staged + all waves done reading buf[ss&1]
  }

  // ---- epilogue: l-reduce, O/l + V residual ----
  const uint2* Vb2 = (const uint2*)Vb;
#pragma unroll
  for (int tb = 0; tb < 2; ++tb) {
    const float l = lsum[tb] + __shfl_xor(lsum[tb], 32, 64);
    const float inv = 1.0f / l;                // valid at t-local = l31
    const int T32 = 2 * T64 + tb;
#pragma unroll
    for (int db = 0; db < 2; ++db) {
#pragma unroll
      for (int rq = 0; rq < 4; ++rq) {
        const int sq = 8 * T32 + 2 * rq + h;   // t-quad (4 consecutive t)
        uint2 vr = Vb2[(((size_t)(bh * 32 + (sq >> 4)) * 4 + ((sq >> 2) & 3)) * 2 + db) * 128
                       + l31 * 4 + ((sq >> 1) & 1) * 2 + (sq & 1)];
        float vres[4];
        vres[0] = bf2f((ushort)(vr.x & 0xFFFFu));
        vres[1] = bf2f((ushort)(vr.x >> 16));
        vres[2] = bf2f((ushort)(vr.y & 0xFFFFu));
        vres[3] = bf2f((ushort)(vr.y >> 16));
#pragma unroll
        for (int rr = 0; rr < 4; ++rr) {
          const int row = rr + 8 * rq + 4 * h;          // t-local in [0,32)
          const float iT = __shfl(inv, row, 64);
          const int t = T32 * 32 + row;
          out[((size_t)(b * T_SEQ + t)) * EMB + hh * D_H + db * 32 + l31] =
              oacc[tb][db][rq * 4 + rr] * iT + vres[rr];
        }
      }
    }
  }
}

extern "C" void kernel_launch(void* const* d_in, const int* in_sizes, int n_in,
                              void* d_out, int out_size, void* d_ws, size_t ws_size,
                              hipStream_t stream) {
  const float* x  = (const float*)d_in[0];
  const float* Wq = (const float*)d_in[1];
  const float* Wk = (const float*)d_in[2];
  const float* Wv = (const float*)d_in[3];
  float* out = (float*)d_out;

  const size_t per4 = (size_t)64 * 64 * 4 * 64;  // 1,048,576 uint4 per blob (16 MB)
  uint4* Qb = (uint4*)d_ws;
  uint4* Kb = Qb + per4;
  uint4* Vb = Kb + per4;
  ushort* Wb = (ushort*)(Vb + per4);  // 24 KB of bf16 W fragments
  // ws needed: 3 * 16.78 MB + 24 KB = 50.4 MB

  wconv<<<1, 64, 0, stream>>>(Wq, Wk, Wv, Wb);
  proj_qkv<<<2048, 256, 0, stream>>>(x, Wb, (uint2*)Qb, (uint2*)Kb, (uint2*)Vb);
  attn_fused<<<512, 256, 0, stream>>>(Qb, Kb, Vb, out);
}

// Round 8
// 176.675 us; speedup vs baseline: 1.0298x; 1.0298x over previous
//
#include <hip/hip_runtime.h>

#define T_SEQ 2048
#define N_B   4
#define N_H   16
#define D_H   64
#define EMB   1024
#define CSC   0.18033688011f  // log2(e) / sqrt(64), folded into Q at projection

typedef __attribute__((ext_vector_type(8))) short   vshort8;   // 8 bf16 (4 VGPRs)
typedef __attribute__((ext_vector_type(4))) float   vfloat4;   // 16x16 C/D
typedef __attribute__((ext_vector_type(16))) float  vfloat16;  // 32x32 C/D

__device__ __forceinline__ ushort f2bf(float f) {
  union { float f; unsigned u; } v; v.f = f;
  unsigned u = v.u;
  return (ushort)((u + 0x7fffu + ((u >> 16) & 1u)) >> 16);  // RNE
}
__device__ __forceinline__ unsigned pk2bf(float a, float b) {  // [bf(a),bf(b)] in mem
  return (unsigned)f2bf(a) | ((unsigned)f2bf(b) << 16);
}
__device__ __forceinline__ float bf2f(ushort b) {
  union { unsigned u; float f; } v; v.u = ((unsigned)b) << 16;
  return v.f;
}
__device__ __forceinline__ float fexp2(float x) {
#if __has_builtin(__builtin_amdgcn_exp2f)
  return __builtin_amdgcn_exp2f(x);
#else
  return exp2f(x);
#endif
}
// pack hi16(lo),hi16(hi) -> [bf_trunc(lo), bf_trunc(hi)] in memory (1 v_perm)
__device__ __forceinline__ unsigned permhi(float hi, float lo) {
  union { float f; unsigned u; } a, b; a.f = hi; b.f = lo;
#if __has_builtin(__builtin_amdgcn_perm)
  return __builtin_amdgcn_perm(a.u, b.u, 0x07060302u);
#else
  return (a.u & 0xFFFF0000u) | (b.u >> 16);
#endif
}
// v_permlane32_swap_b32: cross-half exchange for the P C->A transpose.
//   a' = { a (lanes<32) | b[lane-32] (lanes>=32) }
//   b' = { a[lane+32] (lanes<32) | b (lanes>=32) }
__device__ __forceinline__ void plswap(unsigned &a, unsigned &b) {
  asm("v_permlane32_swap_b32 %0, %1" : "+v"(a), "+v"(b));
}
__device__ __forceinline__ vshort8 cvt8(const float* p) {
  float4 w0 = *(const float4*)(p);
  float4 w1 = *(const float4*)(p + 4);
  vshort8 t;
  t[0] = (short)f2bf(w0.x); t[1] = (short)f2bf(w0.y);
  t[2] = (short)f2bf(w0.z); t[3] = (short)f2bf(w0.w);
  t[4] = (short)f2bf(w1.x); t[5] = (short)f2bf(w1.y);
  t[6] = (short)f2bf(w1.z); t[7] = (short)f2bf(w1.w);
  return t;
}

// ---- 32-lane-fragment blob layouts (uint4 = 8 bf16 = one lane-frag) ----
// Q/K: uint4 idx = ((bh*64 + t32)*4 + dstep)*64 + l31*2 + h
//      lane (l31,h) frag = X[t = 32*t32 + l31][d = 16*dstep + 8*h + 0..7]
// V  : uint4 idx = (((bh*32 + s64)*4 + step)*2 + dblk)*64 + l31*2 + h
//      lane (l31,h) frag = V[s = 64*s64 + 16*step + 8*h + 0..7][d = 32*dblk + l31]

// ------- QKV projection (16x16 MFMA compute, 32-frag stores) ---------------
// W conversion fused in-kernel: 4 waves cooperatively convert the 3 weight
// matrices (24 lane-fragment groups, 6 cvt8/wave) into LDS once per block,
// one barrier, then the m-loop reads fragments from LDS.  Replaces the
// separate 1-wave wconv kernel (saves a launch + GPU serialization).
__global__ __launch_bounds__(256, 4) void proj_qkv(
    const float* __restrict__ x, const float* __restrict__ Wq,
    const float* __restrict__ Wk, const float* __restrict__ Wv,
    uint2* __restrict__ Qb, uint2* __restrict__ Kb, uint2* __restrict__ Vb) {
  const int wid  = threadIdx.x >> 6;
  const int lane = threadIdx.x & 63;
  const int l15  = lane & 15;
  const int q    = lane >> 4;
  const int gw    = blockIdx.x * 4 + wid;   // [0,8192)
  const int strip = gw >> 4;                // 16-row strip over B*T
  const int hd    = gw & 15;
  const int r0    = strip * 16;
  const int b     = r0 >> 11;
  const int bh    = b * N_H + hd;
  const int ts    = (r0 & (T_SEQ - 1)) >> 4;  // strip index within head [0,128)

  // ---- cooperative W conversion into LDS (layout == old Wb blob) ----
  __shared__ ushort Wl[24 * 64 * 8];   // 24 KB
#pragma unroll
  for (int fi = 0; fi < 6; ++fi) {
    const int f  = wid + fi * 4;             // frag group = (m*2+kc)*4+nt
    const int m  = f >> 3, kc = (f >> 2) & 1, nt = f & 3;
    const float* wsrc = (m == 0) ? Wq : (m == 1) ? Wk : Wv;
    vshort8 t = cvt8(wsrc + (nt * 16 + l15) * D_H + kc * 32 + q * 8);
    *(vshort8*)(&Wl[(f * 64 + lane) * 8]) = t;
  }

  // x frag: lane holds x[r0+l15][hd*64 + kc*32 + q*8 + j]
  vshort8 afr[2];
  {
    const float* xp = x + (size_t)(r0 + l15) * EMB + hd * D_H + q * 8;
    afr[0] = cvt8(xp);
    afr[1] = cvt8(xp + 32);
  }
  __syncthreads();                           // W fragments landed

  uint2* Bs[3] = {Qb, Kb, Vb};
#pragma unroll
  for (int m = 0; m < 3; ++m) {
    vshort8 wf[2][4];
#pragma unroll
    for (int kc = 0; kc < 2; ++kc)
#pragma unroll
      for (int nt = 0; nt < 4; ++nt)
        wf[kc][nt] = *(const vshort8*)(&Wl[(((m * 2 + kc) * 4 + nt) * 64 + lane) * 8]);
    vfloat4 acc[4];
#pragma unroll
    for (int nt = 0; nt < 4; ++nt) acc[nt] = (vfloat4){0.f, 0.f, 0.f, 0.f};
#pragma unroll
    for (int kc = 0; kc < 2; ++kc)
#pragma unroll
      for (int nt = 0; nt < 4; ++nt)
        acc[nt] = (m < 2)
          ? __builtin_amdgcn_mfma_f32_16x16x32_bf16(wf[kc][nt], afr[kc], acc[nt], 0, 0, 0)
          : __builtin_amdgcn_mfma_f32_16x16x32_bf16(afr[kc], wf[kc][nt], acc[nt], 0, 0, 0);
    uint2* B = Bs[m];
#pragma unroll
    for (int nt = 0; nt < 4; ++nt) {
      vfloat4 a = acc[nt];
      if (m == 0) { a[0] *= CSC; a[1] *= CSC; a[2] *= CSC; a[3] *= CSC; }
      uint2 w;
      w.x = pk2bf(a[0], a[1]);
      w.y = pk2bf(a[2], a[3]);
      size_t idx;
      if (m < 2) {
        // swapped C: lane holds (d = 16nt+4q+r, t = l15); t32 = ts>>1
        idx = ((size_t)(bh * 64 + (ts >> 1)) * 4 + nt) * 128
              + (l15 + 16 * (ts & 1)) * 4 + q;
      } else {
        // normal C: lane holds (s = 16(ts&3)+4q+r local in s64, d = 16nt+l15)
        idx = (((size_t)(bh * 32 + (ts >> 2)) * 4 + (ts & 3)) * 2 + (nt >> 1)) * 128
              + 64 * (nt & 1) + l15 * 4 + q;
      }
      B[idx] = w;
    }
  }
}

// ---------------- fused flash attention (no-max softmax) + V residual -------
// ROUND-0 STRUCTURE RESTORED (proven 83.5us / 124 VGPR clean): wave = 64
// q-rows, block = 4 waves of one (b,h), global K/V loads, zero LDS, zero
// barriers, 512 blocks -> waves drift freely and cover each other's stalls.
// r4-r7 lesson: oacc+sacc fill the AGPR half of the unified file; arch VGPRs
// cap at ~128, so ANY added state (prefetch bufs, stage ptrs) spills.  Only
// register-NEUTRAL/NEGATIVE upgrades are kept (all validated passing r1-r7):
//  - permlane32_swap P-transpose: 16 ds_bpermute + ~48 cndmask -> 16 permlane
//    per tile, and saves ~10 arch regs vs the shfl mux (T12, 1.20x prim.)
//  - 4-way partial exp sums (breaks 32-deep serial v_add chain)
//  - s_setprio(1) around MFMA clusters (m191: +4-7% in this regime)
__global__ __launch_bounds__(256, 2) void attn_fused(
    const uint4* __restrict__ Qb, const uint4* __restrict__ Kb,
    const uint4* __restrict__ Vb, float* __restrict__ out) {
  const int tid  = threadIdx.x;
  const int wid  = tid >> 6;
  const int lane = tid & 63;
  const int l31  = lane & 31;
  const int h    = lane >> 5;

  // XCD swizzle: 16 consecutive per-XCD slots share a bh -> K/V stay in that L2
  const int blk  = blockIdx.x;                 // [0,512)
  const int work = (blk & 7) * 64 + (blk >> 3);
  const int bh   = work >> 3;
  const int tblk8 = work & 7;
  const int b = bh >> 4, hh = bh & 15;
  const int T64 = tblk8 * 4 + wid;             // this wave's 64-t chunk [0,32)

  const int lo = l31 * 2 + h;                  // lane offset in uint4 units

  // Q B-frags: lane holds Q[t = 32*t32 + l31][d = 16ds + 8h + j] * CSC
  vshort8 qf[2][4];
#pragma unroll
  for (int tb = 0; tb < 2; ++tb)
#pragma unroll
    for (int ds = 0; ds < 4; ++ds)
      qf[tb][ds] = *(const vshort8*)&Qb[((size_t)(bh * 64 + 2 * T64 + tb) * 4 + ds) * 64 + lo];

  vfloat16 oacc[2][2];
#pragma unroll
  for (int tb = 0; tb < 2; ++tb)
#pragma unroll
    for (int db = 0; db < 2; ++db)
#pragma unroll
      for (int i = 0; i < 16; ++i) oacc[tb][db][i] = 0.f;
  float lsum[2] = {0.f, 0.f};

#pragma unroll 1
  for (int ss = 0; ss < 32; ++ss) {  // 32 s-tiles of 64
    // K A-frags: lane holds K[s = 64ss + 32sb + l31][d = 16ds + 8h + j]
    vshort8 kf[2][4];
#pragma unroll
    for (int sb = 0; sb < 2; ++sb)
#pragma unroll
      for (int ds = 0; ds < 4; ++ds)
        kf[sb][ds] = *(const vshort8*)&Kb[((size_t)(bh * 64 + 2 * ss + sb) * 4 + ds) * 64 + lo];
    // V B-frags: lane holds V[s = 64ss + 16st + 8h + j][d = 32db + l31]
    vshort8 vf[4][2];
#pragma unroll
    for (int st = 0; st < 4; ++st)
#pragma unroll
      for (int db = 0; db < 2; ++db)
        vf[st][db] = *(const vshort8*)&Vb[(((size_t)(bh * 32 + ss) * 4 + st) * 2 + db) * 64 + lo];

#pragma unroll
    for (int tb = 0; tb < 2; ++tb) {
      // S^T = K*Q^T : C holds (s-local = (r&3)+8(r>>2)+4h + 32sb, t = l31)
      vfloat16 sacc[2];
#pragma unroll
      for (int sb = 0; sb < 2; ++sb)
#pragma unroll
        for (int i = 0; i < 16; ++i) sacc[sb][i] = 0.f;
      __builtin_amdgcn_s_setprio(1);
#pragma unroll
      for (int sb = 0; sb < 2; ++sb)
#pragma unroll
        for (int ds = 0; ds < 4; ++ds)
          sacc[sb] = __builtin_amdgcn_mfma_f32_32x32x16_bf16(kf[sb][ds], qf[tb][ds], sacc[sb], 0, 0, 0);
      __builtin_amdgcn_s_setprio(0);

      // no-max softmax, 4-way partial sums (breaks the serial add chain)
      float p[2][16];
      float s0 = 0.f, s1 = 0.f, s2 = 0.f, s3 = 0.f;
#pragma unroll
      for (int sb = 0; sb < 2; ++sb)
#pragma unroll
        for (int r = 0; r < 16; r += 4) {
          p[sb][r + 0] = fexp2(sacc[sb][r + 0]); s0 += p[sb][r + 0];
          p[sb][r + 1] = fexp2(sacc[sb][r + 1]); s1 += p[sb][r + 1];
          p[sb][r + 2] = fexp2(sacc[sb][r + 2]); s2 += p[sb][r + 2];
          p[sb][r + 3] = fexp2(sacc[sb][r + 3]); s3 += p[sb][r + 3];
        }
      lsum[tb] += (s0 + s1) + (s2 + s3);

      // in-register C->A transpose of P via permlane32_swap:
      // own packs: OL = s 16g+4h+{0..3}, OH = s 16g+8+4h+{0..3} (local in sb)
#pragma unroll
      for (int sb = 0; sb < 2; ++sb)
#pragma unroll
        for (int g = 0; g < 2; ++g) {
          unsigned OL0 = permhi(p[sb][8 * g + 1], p[sb][8 * g + 0]);
          unsigned OL1 = permhi(p[sb][8 * g + 3], p[sb][8 * g + 2]);
          unsigned OH0 = permhi(p[sb][8 * g + 5], p[sb][8 * g + 4]);
          unsigned OH1 = permhi(p[sb][8 * g + 7], p[sb][8 * g + 6]);
          plswap(OL0, OH0);   // OL0' = {own OL0 | partner OH0}, OH0' = {partner OL0 | own OH0}
          plswap(OL1, OH1);
          union { unsigned u[4]; vshort8 v; } pa;
          pa.u[0] = OL0; pa.u[1] = OL1; pa.u[2] = OH0; pa.u[3] = OH1;
          const int st = 2 * sb + g;
          __builtin_amdgcn_s_setprio(1);
#pragma unroll
          for (int db = 0; db < 2; ++db)
            oacc[tb][db] = __builtin_amdgcn_mfma_f32_32x32x16_bf16(pa.v, vf[st][db], oacc[tb][db], 0, 0, 0);
          __builtin_amdgcn_s_setprio(0);
        }
    }
  }

  // ---- epilogue: l-reduce, O/l + V residual ----
  const uint2* Vb2 = (const uint2*)Vb;
#pragma unroll
  for (int tb = 0; tb < 2; ++tb) {
    const float l = lsum[tb] + __shfl_xor(lsum[tb], 32, 64);
    const float inv = 1.0f / l;                // valid at t-local = l31
    const int T32 = 2 * T64 + tb;
#pragma unroll
    for (int db = 0; db < 2; ++db) {
#pragma unroll
      for (int rq = 0; rq < 4; ++rq) {
        const int sq = 8 * T32 + 2 * rq + h;   // t-quad (4 consecutive t)
        uint2 vr = Vb2[(((size_t)(bh * 32 + (sq >> 4)) * 4 + ((sq >> 2) & 3)) * 2 + db) * 128
                       + l31 * 4 + ((sq >> 1) & 1) * 2 + (sq & 1)];
        float vres[4];
        vres[0] = bf2f((ushort)(vr.x & 0xFFFFu));
        vres[1] = bf2f((ushort)(vr.x >> 16));
        vres[2] = bf2f((ushort)(vr.y & 0xFFFFu));
        vres[3] = bf2f((ushort)(vr.y >> 16));
#pragma unroll
        for (int rr = 0; rr < 4; ++rr) {
          const int row = rr + 8 * rq + 4 * h;          // t-local in [0,32)
          const float iT = __shfl(inv, row, 64);
          const int t = T32 * 32 + row;
          out[((size_t)(b * T_SEQ + t)) * EMB + hh * D_H + db * 32 + l31] =
              oacc[tb][db][rq * 4 + rr] * iT + vres[rr];
        }
      }
    }
  }
}

extern "C" void kernel_launch(void* const* d_in, const int* in_sizes, int n_in,
                              void* d_out, int out_size, void* d_ws, size_t ws_size,
                              hipStream_t stream) {
  const float* x  = (const float*)d_in[0];
  const float* Wq = (const float*)d_in[1];
  const float* Wk = (const float*)d_in[2];
  const float* Wv = (const float*)d_in[3];
  float* out = (float*)d_out;

  const size_t per4 = (size_t)64 * 64 * 4 * 64;  // 1,048,576 uint4 per blob (16 MB)
  uint4* Qb = (uint4*)d_ws;
  uint4* Kb = Qb + per4;
  uint4* Vb = Kb + per4;
  // ws needed: 3 * 16.78 MB = 50.3 MB

  proj_qkv<<<2048, 256, 0, stream>>>(x, Wq, Wk, Wv,
                                     (uint2*)Qb, (uint2*)Kb, (uint2*)Vb);
  attn_fused<<<512, 256, 0, stream>>>(Qb, Kb, Vb, out);
}

// Round 9
// 172.125 us; speedup vs baseline: 1.0571x; 1.0264x over previous
//
#include <hip/hip_runtime.h>

#define T_SEQ 2048
#define N_B   4
#define N_H   16
#define D_H   64
#define EMB   1024
#define CSC   0.18033688011f  // log2(e) / sqrt(64), folded into Q at projection

typedef __attribute__((ext_vector_type(8))) short   vshort8;   // 8 bf16 (4 VGPRs)
typedef __attribute__((ext_vector_type(4))) float   vfloat4;   // 16x16 C/D
typedef __attribute__((ext_vector_type(16))) float  vfloat16;  // 32x32 C/D

__device__ __forceinline__ ushort f2bf(float f) {
  union { float f; unsigned u; } v; v.f = f;
  unsigned u = v.u;
  return (ushort)((u + 0x7fffu + ((u >> 16) & 1u)) >> 16);  // RNE
}
__device__ __forceinline__ unsigned pk2bf(float a, float b) {  // [bf(a),bf(b)] in mem
  return (unsigned)f2bf(a) | ((unsigned)f2bf(b) << 16);
}
__device__ __forceinline__ float bf2f(ushort b) {
  union { unsigned u; float f; } v; v.u = ((unsigned)b) << 16;
  return v.f;
}
__device__ __forceinline__ float fexp2(float x) {
#if __has_builtin(__builtin_amdgcn_exp2f)
  return __builtin_amdgcn_exp2f(x);
#else
  return exp2f(x);
#endif
}
// pack hi16(lo),hi16(hi) -> [bf_trunc(lo), bf_trunc(hi)] in memory (1 v_perm)
__device__ __forceinline__ unsigned permhi(float hi, float lo) {
  union { float f; unsigned u; } a, b; a.f = hi; b.f = lo;
#if __has_builtin(__builtin_amdgcn_perm)
  return __builtin_amdgcn_perm(a.u, b.u, 0x07060302u);
#else
  return (a.u & 0xFFFF0000u) | (b.u >> 16);
#endif
}
__device__ __forceinline__ vshort8 cvt8(const float* p) {
  float4 w0 = *(const float4*)(p);
  float4 w1 = *(const float4*)(p + 4);
  vshort8 t;
  t[0] = (short)f2bf(w0.x); t[1] = (short)f2bf(w0.y);
  t[2] = (short)f2bf(w0.z); t[3] = (short)f2bf(w0.w);
  t[4] = (short)f2bf(w1.x); t[5] = (short)f2bf(w1.y);
  t[6] = (short)f2bf(w1.z); t[7] = (short)f2bf(w1.w);
  return t;
}

// ---- 32-lane-fragment blob layouts (uint4 = 8 bf16 = one lane-frag) ----
// Q/K: uint4 idx = ((bh*64 + t32)*4 + dstep)*64 + l31*2 + h
//      lane (l31,h) frag = X[t = 32*t32 + l31][d = 16*dstep + 8*h + 0..7]
// V  : uint4 idx = (((bh*32 + s64)*4 + step)*2 + dblk)*64 + l31*2 + h
//      lane (l31,h) frag = V[s = 64*s64 + 16*step + 8*h + 0..7][d = 32*dblk + l31]

// ------- QKV projection (16x16 MFMA compute, 32-frag stores) ---------------
// W conversion fused in-kernel (r8, validated: non-attn time 92.2 -> 84.7us):
// 4 waves cooperatively convert the 3 weight matrices into LDS once per
// block, one barrier, then the m-loop reads fragments from LDS.
__global__ __launch_bounds__(256, 4) void proj_qkv(
    const float* __restrict__ x, const float* __restrict__ Wq,
    const float* __restrict__ Wk, const float* __restrict__ Wv,
    uint2* __restrict__ Qb, uint2* __restrict__ Kb, uint2* __restrict__ Vb) {
  const int wid  = threadIdx.x >> 6;
  const int lane = threadIdx.x & 63;
  const int l15  = lane & 15;
  const int q    = lane >> 4;
  const int gw    = blockIdx.x * 4 + wid;   // [0,8192)
  const int strip = gw >> 4;                // 16-row strip over B*T
  const int hd    = gw & 15;
  const int r0    = strip * 16;
  const int b     = r0 >> 11;
  const int bh    = b * N_H + hd;
  const int ts    = (r0 & (T_SEQ - 1)) >> 4;  // strip index within head [0,128)

  // ---- cooperative W conversion into LDS (layout == old Wb blob) ----
  __shared__ ushort Wl[24 * 64 * 8];   // 24 KB
#pragma unroll
  for (int fi = 0; fi < 6; ++fi) {
    const int f  = wid + fi * 4;             // frag group = (m*2+kc)*4+nt
    const int m  = f >> 3, kc = (f >> 2) & 1, nt = f & 3;
    const float* wsrc = (m == 0) ? Wq : (m == 1) ? Wk : Wv;
    vshort8 t = cvt8(wsrc + (nt * 16 + l15) * D_H + kc * 32 + q * 8);
    *(vshort8*)(&Wl[(f * 64 + lane) * 8]) = t;
  }

  // x frag: lane holds x[r0+l15][hd*64 + kc*32 + q*8 + j]
  vshort8 afr[2];
  {
    const float* xp = x + (size_t)(r0 + l15) * EMB + hd * D_H + q * 8;
    afr[0] = cvt8(xp);
    afr[1] = cvt8(xp + 32);
  }
  __syncthreads();                           // W fragments landed

  uint2* Bs[3] = {Qb, Kb, Vb};
#pragma unroll
  for (int m = 0; m < 3; ++m) {
    vshort8 wf[2][4];
#pragma unroll
    for (int kc = 0; kc < 2; ++kc)
#pragma unroll
      for (int nt = 0; nt < 4; ++nt)
        wf[kc][nt] = *(const vshort8*)(&Wl[(((m * 2 + kc) * 4 + nt) * 64 + lane) * 8]);
    vfloat4 acc[4];
#pragma unroll
    for (int nt = 0; nt < 4; ++nt) acc[nt] = (vfloat4){0.f, 0.f, 0.f, 0.f};
#pragma unroll
    for (int kc = 0; kc < 2; ++kc)
#pragma unroll
      for (int nt = 0; nt < 4; ++nt)
        acc[nt] = (m < 2)
          ? __builtin_amdgcn_mfma_f32_16x16x32_bf16(wf[kc][nt], afr[kc], acc[nt], 0, 0, 0)
          : __builtin_amdgcn_mfma_f32_16x16x32_bf16(afr[kc], wf[kc][nt], acc[nt], 0, 0, 0);
    uint2* B = Bs[m];
#pragma unroll
    for (int nt = 0; nt < 4; ++nt) {
      vfloat4 a = acc[nt];
      if (m == 0) { a[0] *= CSC; a[1] *= CSC; a[2] *= CSC; a[3] *= CSC; }
      uint2 w;
      w.x = pk2bf(a[0], a[1]);
      w.y = pk2bf(a[2], a[3]);
      size_t idx;
      if (m < 2) {
        // swapped C: lane holds (d = 16nt+4q+r, t = l15); t32 = ts>>1
        idx = ((size_t)(bh * 64 + (ts >> 1)) * 4 + nt) * 128
              + (l15 + 16 * (ts & 1)) * 4 + q;
      } else {
        // normal C: lane holds (s = 16(ts&3)+4q+r local in s64, d = 16nt+l15)
        idx = (((size_t)(bh * 32 + (ts >> 2)) * 4 + (ts & 3)) * 2 + (nt >> 1)) * 128
              + 64 * (nt & 1) + l15 * 4 + q;
      }
      B[idx] = w;
    }
  }
}

// ---------------- fused flash attention (no-max softmax) + V residual -------
// EXACT round-0 inner loop (83.5us, 124 VGPR, zero scratch — reproduced
// twice).  Wave = 64 q-rows (2 t32-blocks), block = 4 waves of one (b,h),
// global K/V loads, zero LDS, zero barriers; waves drift freely.
// r4-r8 lesson: oacc+sacc fill the accumulator half of the unified file;
// the arch-VGPR cap at 2 waves/SIMD is ~128 and r0's codegen sits at 124.
// Even "neutral" additions (plswap tied-asm, setprio, partial-sum temps)
// tip it into scratch (r8: 128 VGPR + 4.6MB WRITE spill, 92us).  Do not
// add state to this loop.
__global__ __launch_bounds__(256, 2) void attn_fused(
    const uint4* __restrict__ Qb, const uint4* __restrict__ Kb,
    const uint4* __restrict__ Vb, float* __restrict__ out) {
  const int tid  = threadIdx.x;
  const int wid  = tid >> 6;
  const int lane = tid & 63;
  const int l31  = lane & 31;
  const int h    = lane >> 5;

  // XCD swizzle: 16 consecutive per-XCD slots share a bh -> K/V stay in that L2
  const int blk  = blockIdx.x;                 // [0,512)
  const int work = (blk & 7) * 64 + (blk >> 3);
  const int bh   = work >> 3;
  const int tblk8 = work & 7;
  const int b = bh >> 4, hh = bh & 15;
  const int T64 = tblk8 * 4 + wid;             // this wave's 64-t chunk [0,32)

  const int lo = l31 * 2 + h;                  // lane offset in uint4 units

  // Q B-frags: lane holds Q[t = 32*t32 + l31][d = 16ds + 8h + j] * CSC
  vshort8 qf[2][4];
#pragma unroll
  for (int tb = 0; tb < 2; ++tb)
#pragma unroll
    for (int ds = 0; ds < 4; ++ds)
      qf[tb][ds] = *(const vshort8*)&Qb[((size_t)(bh * 64 + 2 * T64 + tb) * 4 + ds) * 64 + lo];

  vfloat16 oacc[2][2];
#pragma unroll
  for (int tb = 0; tb < 2; ++tb)
#pragma unroll
    for (int db = 0; db < 2; ++db)
#pragma unroll
      for (int i = 0; i < 16; ++i) oacc[tb][db][i] = 0.f;
  float lsum[2] = {0.f, 0.f};

#pragma unroll 1
  for (int ss = 0; ss < 32; ++ss) {  // 32 s-tiles of 64
    // K A-frags: lane holds K[s = 64ss + 32sb + l31][d = 16ds + 8h + j]
    vshort8 kf[2][4];
#pragma unroll
    for (int sb = 0; sb < 2; ++sb)
#pragma unroll
      for (int ds = 0; ds < 4; ++ds)
        kf[sb][ds] = *(const vshort8*)&Kb[((size_t)(bh * 64 + 2 * ss + sb) * 4 + ds) * 64 + lo];
    // V B-frags: lane holds V[s = 64ss + 16st + 8h + j][d = 32db + l31]
    vshort8 vf[4][2];
#pragma unroll
    for (int st = 0; st < 4; ++st)
#pragma unroll
      for (int db = 0; db < 2; ++db)
        vf[st][db] = *(const vshort8*)&Vb[(((size_t)(bh * 32 + ss) * 4 + st) * 2 + db) * 64 + lo];

#pragma unroll
    for (int tb = 0; tb < 2; ++tb) {
      // S^T = K*Q^T : C holds (s-local = (r&3)+8(r>>2)+4h + 32sb, t = l31)
      vfloat16 sacc[2];
#pragma unroll
      for (int sb = 0; sb < 2; ++sb) {
#pragma unroll
        for (int i = 0; i < 16; ++i) sacc[sb][i] = 0.f;
#pragma unroll
        for (int ds = 0; ds < 4; ++ds)
          sacc[sb] = __builtin_amdgcn_mfma_f32_32x32x16_bf16(kf[sb][ds], qf[tb][ds], sacc[sb], 0, 0, 0);
      }
      // no-max softmax + in-register C->A transpose of P
      float p[2][16];
      float ls = 0.f;
#pragma unroll
      for (int sb = 0; sb < 2; ++sb)
#pragma unroll
        for (int r = 0; r < 16; ++r) {
          p[sb][r] = fexp2(sacc[sb][r]);
          ls += p[sb][r];
        }
      lsum[tb] += ls;

#pragma unroll
      for (int sb = 0; sb < 2; ++sb)
#pragma unroll
        for (int g = 0; g < 2; ++g) {
          // own packs: OL = s 16g+4h+{0..3}, OH = s 16g+8+4h+{0..3} (local in sb)
          const unsigned OL0 = permhi(p[sb][8 * g + 1], p[sb][8 * g + 0]);
          const unsigned OL1 = permhi(p[sb][8 * g + 3], p[sb][8 * g + 2]);
          const unsigned OH0 = permhi(p[sb][8 * g + 5], p[sb][8 * g + 4]);
          const unsigned OH1 = permhi(p[sb][8 * g + 7], p[sb][8 * g + 6]);
          // exchange: h=0 needs partner's OL, h=1 needs partner's OH
          const unsigned s0 = h ? OL0 : OH0;
          const unsigned s1 = h ? OL1 : OH1;
          const unsigned r0 = (unsigned)__shfl_xor((int)s0, 32, 64);
          const unsigned r1 = (unsigned)__shfl_xor((int)s1, 32, 64);
          union { unsigned u[4]; vshort8 v; } pa;
          pa.u[0] = h ? r0 : OL0;
          pa.u[1] = h ? r1 : OL1;
          pa.u[2] = h ? OH0 : r0;
          pa.u[3] = h ? OH1 : r1;
          const int st = 2 * sb + g;
#pragma unroll
          for (int db = 0; db < 2; ++db)
            oacc[tb][db] = __builtin_amdgcn_mfma_f32_32x32x16_bf16(pa.v, vf[st][db], oacc[tb][db], 0, 0, 0);
        }
    }
  }

  // ---- epilogue: l-reduce, O/l + V residual ----
  const uint2* Vb2 = (const uint2*)Vb;
#pragma unroll
  for (int tb = 0; tb < 2; ++tb) {
    const float l = lsum[tb] + __shfl_xor(lsum[tb], 32, 64);
    const float inv = 1.0f / l;                // valid at t-local = l31
    const int T32 = 2 * T64 + tb;
#pragma unroll
    for (int db = 0; db < 2; ++db) {
#pragma unroll
      for (int rq = 0; rq < 4; ++rq) {
        const int sq = 8 * T32 + 2 * rq + h;   // t-quad (4 consecutive t)
        uint2 vr = Vb2[(((size_t)(bh * 32 + (sq >> 4)) * 4 + ((sq >> 2) & 3)) * 2 + db) * 128
                       + l31 * 4 + ((sq >> 1) & 1) * 2 + (sq & 1)];
        float vres[4];
        vres[0] = bf2f((ushort)(vr.x & 0xFFFFu));
        vres[1] = bf2f((ushort)(vr.x >> 16));
        vres[2] = bf2f((ushort)(vr.y & 0xFFFFu));
        vres[3] = bf2f((ushort)(vr.y >> 16));
#pragma unroll
        for (int rr = 0; rr < 4; ++rr) {
          const int row = rr + 8 * rq + 4 * h;          // t-local in [0,32)
          const float iT = __shfl(inv, row, 64);
          const int t = T32 * 32 + row;
          out[((size_t)(b * T_SEQ + t)) * EMB + hh * D_H + db * 32 + l31] =
              oacc[tb][db][rq * 4 + rr] * iT + vres[rr];
        }
      }
    }
  }
}

extern "C" void kernel_launch(void* const* d_in, const int* in_sizes, int n_in,
                              void* d_out, int out_size, void* d_ws, size_t ws_size,
                              hipStream_t stream) {
  const float* x  = (const float*)d_in[0];
  const float* Wq = (const float*)d_in[1];
  const float* Wk = (const float*)d_in[2];
  const float* Wv = (const float*)d_in[3];
  float* out = (float*)d_out;

  const size_t per4 = (size_t)64 * 64 * 4 * 64;  // 1,048,576 uint4 per blob (16 MB)
  uint4* Qb = (uint4*)d_ws;
  uint4* Kb = Qb + per4;
  uint4* Vb = Kb + per4;
  // ws needed: 3 * 16.78 MB = 50.3 MB

  proj_qkv<<<2048, 256, 0, stream>>>(x, Wq, Wk, Wv,
                                     (uint2*)Qb, (uint2*)Kb, (uint2*)Vb);
  attn_fused<<<512, 256, 0, stream>>>(Qb, Kb, Vb, out);
}